// Round 1
// baseline (1017.630 us; speedup 1.0000x reference)
//
#include <hip/hip_runtime.h>
#include <hip/hip_bf16.h>
#include <stdint.h>

#define TT 256
#define DD 2048
#define II 5632
#define EE 8
#define PP 2306868   // (II*DD + 4) / 5

typedef __attribute__((ext_vector_type(8))) short bf16x8;
typedef __attribute__((ext_vector_type(4))) float f32x4;

__device__ __forceinline__ ushort f2b_rne(float f) {
  __hip_bfloat16 h = __float2bfloat16(f);
  return __builtin_bit_cast(ushort, h);
}
// exact values only (ints up to 2^8, ternary): truncation is exact
__device__ __forceinline__ ushort f2b_exact(float f) {
  return (ushort)(__builtin_bit_cast(uint32_t, f) >> 16);
}

// ---------------------------------------------------------------- router
__global__ __launch_bounds__(64) void k_router(const float* __restrict__ x,
                                               const float* __restrict__ rw,
                                               int* __restrict__ cnt,
                                               int* __restrict__ tok,
                                               float* __restrict__ tokg) {
  const int t = blockIdx.x;
  const int lane = threadIdx.x;
  const float* xp = x + t * DD;
  float lg[EE];
#pragma unroll
  for (int e = 0; e < EE; ++e) {
    const float* wp = rw + e * DD;
    float acc = 0.f;
    for (int d = lane; d < DD; d += 64) acc += xp[d] * wp[d];
#pragma unroll
    for (int off = 32; off > 0; off >>= 1) acc += __shfl_down(acc, off, 64);
    lg[e] = acc;
  }
  if (lane == 0) {
    int e1 = 0; float v1 = lg[0];
#pragma unroll
    for (int e = 1; e < EE; ++e) if (lg[e] > v1) { v1 = lg[e]; e1 = e; }
    int e2 = -1; float v2 = -3.4e38f;
#pragma unroll
    for (int e = 0; e < EE; ++e) if (e != e1 && lg[e] > v2) { v2 = lg[e]; e2 = e; }
    float ex2 = __expf(v2 - v1);
    float inv = 1.f / (1.f + ex2);
    int s1 = atomicAdd(&cnt[e1], 1);
    tok[e1 * TT + s1] = t; tokg[e1 * TT + s1] = inv;          // p1
    int s2 = atomicAdd(&cnt[e2], 1);
    tok[e2 * TT + s2] = t; tokg[e2 * TT + s2] = ex2 * inv;    // p2
  }
}

// ---------------------------------------------------------------- x -> bf16
__global__ __launch_bounds__(256) void k_xcast(const float* __restrict__ x,
                                               ushort* __restrict__ xb) {
  int i = (blockIdx.x * 256 + threadIdx.x) * 8;
  float4 a = *(const float4*)(x + i);
  float4 b = *(const float4*)(x + i + 4);
  ushort o[8];
  o[0] = f2b_rne(a.x); o[1] = f2b_rne(a.y); o[2] = f2b_rne(a.z); o[3] = f2b_rne(a.w);
  o[4] = f2b_rne(b.x); o[5] = f2b_rne(b.y); o[6] = f2b_rne(b.z); o[7] = f2b_rne(b.w);
  *(uint4*)(xb + i) = *(uint4*)&o[0];
}

// ------------------------------------------------------- staging helpers
// A tile: 64 rows x 64 cols bf16, rows gathered via rows[] (row<0 -> zeros)
__device__ __forceinline__ void stage_a(const ushort* __restrict__ src, int ld,
                                        const int* rows, int k0,
                                        ushort (*A)[72], int tid) {
#pragma unroll
  for (int it = 0; it < 2; ++it) {
    int slot = tid + it * 256;
    int r = slot >> 3, cg = slot & 7;
    int rg = rows[r];
    uint4 v = make_uint4(0u, 0u, 0u, 0u);
    if (rg >= 0) v = *(const uint4*)(src + (long)rg * ld + k0 + cg * 8);
    *(uint4*)&A[r][cg * 8] = v;
  }
}

// Ternary TQ1_0 tile: 64 rows (weight rows n0..) x 64 cols (k0..) -> bf16 LDS
__device__ __forceinline__ void stage_tern(const int* __restrict__ packed,
                                           int n0, int k0, int din,
                                           ushort (*B)[72], int tid) {
#pragma unroll
  for (int it = 0; it < 2; ++it) {
    int slot = tid + it * 256;
    int r = slot >> 3, j = slot & 7;
    int q = (n0 + r) * din + k0;            // flat start of this row's 64 weights
    int a = (int)((unsigned)q / 5u);
    int bend = (int)(((unsigned)q + 63u) / 5u);
    int pidx = a + 2 * j;
    int c0 = pidx * 5 - q;                  // col of p0's digit0, in [-4, ...)
    uint32_t p0 = (pidx     <= bend) ? (uint32_t)packed[pidx]     : 0u;
    uint32_t p1 = (pidx + 1 <= bend) ? (uint32_t)packed[pidx + 1] : 0u;
#pragma unroll
    for (int i = 0; i < 5; ++i) {
      uint32_t q0 = (p0 * 171u) >> 9; uint32_t d0 = p0 - q0 * 3u;
      uint32_t q1 = (p1 * 171u) >> 9; uint32_t d1 = p1 - q1 * 3u;
      ushort w0 = (d0 == 0u) ? (ushort)0xBF80 : ((d0 == 2u) ? (ushort)0x3F80 : (ushort)0);
      ushort w1 = (d1 == 0u) ? (ushort)0xBF80 : ((d1 == 2u) ? (ushort)0x3F80 : (ushort)0);
      int c = c0 + i;
      if ((unsigned)c < 64u) B[r][c] = w0;
      if ((unsigned)(c + 5) < 64u) B[r][c + 5] = w1;
      p0 = q0; p1 = q1;
    }
  }
}

// int32-stored int8 weight tile -> bf16 LDS (exact)
__device__ __forceinline__ void stage_i8(const int* __restrict__ w,
                                         int n0, int k0, int din,
                                         ushort (*B)[72], int tid) {
  int r = tid >> 2, cg = tid & 3;
  const int4* p = (const int4*)(w + (long)(n0 + r) * din + k0 + cg * 16);
  ushort tmp[16];
#pragma unroll
  for (int v4 = 0; v4 < 4; ++v4) {
    int4 v = p[v4];
    tmp[v4 * 4 + 0] = f2b_exact((float)v.x);
    tmp[v4 * 4 + 1] = f2b_exact((float)v.y);
    tmp[v4 * 4 + 2] = f2b_exact((float)v.z);
    tmp[v4 * 4 + 3] = f2b_exact((float)v.w);
  }
  *(uint4*)&B[r][cg * 16]     = *(uint4*)&tmp[0];
  *(uint4*)&B[r][cg * 16 + 8] = *(uint4*)&tmp[8];
}

// ------------------------------------------------- shared expert: gate/up
__global__ __launch_bounds__(256) void k_sh_gateup(const ushort* __restrict__ xb,
                                                   const int* __restrict__ wg,
                                                   const int* __restrict__ wu,
                                                   const float* __restrict__ sg_,
                                                   const float* __restrict__ su_,
                                                   ushort* __restrict__ hsh) {
  const int n0 = blockIdx.x * 64;      // over II
  const int m0 = blockIdx.y * 64;      // over TT
  const int tid = threadIdx.x;
  __shared__ ushort A[64][72];
  __shared__ ushort Bg[64][72];
  __shared__ ushort Bu[64][72];
  __shared__ int rows[64];
  if (tid < 64) rows[tid] = m0 + tid;
  f32x4 accg[4], accu[4];
#pragma unroll
  for (int m = 0; m < 4; ++m) { accg[m] = {0.f,0.f,0.f,0.f}; accu[m] = {0.f,0.f,0.f,0.f}; }
  const int lane = tid & 63, wid = tid >> 6;
  const int col = lane & 15, kg = lane >> 4;
  for (int kt = 0; kt < DD / 64; ++kt) {
    int k0 = kt * 64;
    __syncthreads();
    stage_a(xb, DD, rows, k0, A, tid);
    stage_i8(wg, n0, k0, DD, Bg, tid);
    stage_i8(wu, n0, k0, DD, Bu, tid);
    __syncthreads();
#pragma unroll
    for (int kh = 0; kh < 2; ++kh) {
      int kc = kh * 32 + kg * 8;
      bf16x8 bg = *(const bf16x8*)&Bg[wid * 16 + col][kc];
      bf16x8 bu = *(const bf16x8*)&Bu[wid * 16 + col][kc];
#pragma unroll
      for (int m = 0; m < 4; ++m) {
        bf16x8 av = *(const bf16x8*)&A[m * 16 + col][kc];
        accg[m] = __builtin_amdgcn_mfma_f32_16x16x32_bf16(av, bg, accg[m], 0, 0, 0);
        accu[m] = __builtin_amdgcn_mfma_f32_16x16x32_bf16(av, bu, accu[m], 0, 0, 0);
      }
    }
  }
  const int n_abs = n0 + wid * 16 + col;
  const float sg = sg_[n_abs];
  const float su = su_[n_abs];
#pragma unroll
  for (int m = 0; m < 4; ++m) {
#pragma unroll
    for (int i = 0; i < 4; ++i) {
      int mr = m * 16 + kg * 4 + i;
      float g = accg[m][i] * sg;
      float u = accu[m][i] * su;
      float h = g / (1.f + __expf(-g)) * u;
      hsh[(long)(m0 + mr) * II + n_abs] = f2b_rne(h);
    }
  }
}

// --------------------------------------------------- shared expert: down
__global__ __launch_bounds__(256) void k_sh_down(const ushort* __restrict__ hsh,
                                                 const int* __restrict__ wd,
                                                 const float* __restrict__ sd_,
                                                 float* __restrict__ out) {
  const int n0 = blockIdx.x * 64;      // over DD
  const int m0 = blockIdx.y * 64;      // over TT
  const int tid = threadIdx.x;
  __shared__ ushort A[64][72];
  __shared__ ushort B[64][72];
  __shared__ int rows[64];
  if (tid < 64) rows[tid] = m0 + tid;
  f32x4 acc[4];
#pragma unroll
  for (int m = 0; m < 4; ++m) acc[m] = {0.f,0.f,0.f,0.f};
  const int lane = tid & 63, wid = tid >> 6;
  const int col = lane & 15, kg = lane >> 4;
  for (int kt = 0; kt < II / 64; ++kt) {
    int k0 = kt * 64;
    __syncthreads();
    stage_a(hsh, II, rows, k0, A, tid);
    stage_i8(wd, n0, k0, II, B, tid);
    __syncthreads();
#pragma unroll
    for (int kh = 0; kh < 2; ++kh) {
      int kc = kh * 32 + kg * 8;
      bf16x8 bv = *(const bf16x8*)&B[wid * 16 + col][kc];
#pragma unroll
      for (int m = 0; m < 4; ++m) {
        bf16x8 av = *(const bf16x8*)&A[m * 16 + col][kc];
        acc[m] = __builtin_amdgcn_mfma_f32_16x16x32_bf16(av, bv, acc[m], 0, 0, 0);
      }
    }
  }
  const int n_abs = n0 + wid * 16 + col;
  const float sd = sd_[n_abs];
#pragma unroll
  for (int m = 0; m < 4; ++m) {
#pragma unroll
    for (int i = 0; i < 4; ++i) {
      int mr = m * 16 + kg * 4 + i;
      out[(long)(m0 + mr) * DD + n_abs] = acc[m][i] * sd;
    }
  }
}

// -------------------------------------------------- routed experts: gate/up
__global__ __launch_bounds__(256) void k_moe_gateup(const ushort* __restrict__ xb,
                                                    const int* __restrict__ gate_p,
                                                    const int* __restrict__ up_p,
                                                    const float* __restrict__ gate_s,
                                                    const float* __restrict__ up_s,
                                                    const int* __restrict__ cnt,
                                                    const int* __restrict__ tok,
                                                    ushort* __restrict__ hrt) {
  const int e = blockIdx.z;
  const int ne = cnt[e];
  const int m0 = blockIdx.y * 64;
  if (m0 >= ne) return;
  const int n0 = blockIdx.x * 64;      // over II
  const int tid = threadIdx.x;
  __shared__ ushort A[64][72];
  __shared__ ushort Bg[64][72];
  __shared__ ushort Bu[64][72];
  __shared__ int rows[64];
  if (tid < 64) {
    int s = m0 + tid;
    rows[tid] = (s < ne) ? tok[e * TT + s] : -1;
  }
  const int* gp = gate_p + (long)e * PP;
  const int* up = up_p + (long)e * PP;
  f32x4 accg[4], accu[4];
#pragma unroll
  for (int m = 0; m < 4; ++m) { accg[m] = {0.f,0.f,0.f,0.f}; accu[m] = {0.f,0.f,0.f,0.f}; }
  const int lane = tid & 63, wid = tid >> 6;
  const int col = lane & 15, kg = lane >> 4;
  for (int kt = 0; kt < DD / 64; ++kt) {
    int k0 = kt * 64;
    __syncthreads();
    stage_a(xb, DD, rows, k0, A, tid);
    stage_tern(gp, n0, k0, DD, Bg, tid);
    stage_tern(up, n0, k0, DD, Bu, tid);
    __syncthreads();
#pragma unroll
    for (int kh = 0; kh < 2; ++kh) {
      int kc = kh * 32 + kg * 8;
      bf16x8 bg = *(const bf16x8*)&Bg[wid * 16 + col][kc];
      bf16x8 bu = *(const bf16x8*)&Bu[wid * 16 + col][kc];
#pragma unroll
      for (int m = 0; m < 4; ++m) {
        bf16x8 av = *(const bf16x8*)&A[m * 16 + col][kc];
        accg[m] = __builtin_amdgcn_mfma_f32_16x16x32_bf16(av, bg, accg[m], 0, 0, 0);
        accu[m] = __builtin_amdgcn_mfma_f32_16x16x32_bf16(av, bu, accu[m], 0, 0, 0);
      }
    }
  }
  const int n_abs = n0 + wid * 16 + col;
  const float sg = gate_s[(long)e * II + n_abs];
  const float su = up_s[(long)e * II + n_abs];
  ushort* hb = hrt + (long)e * TT * II;
#pragma unroll
  for (int m = 0; m < 4; ++m) {
#pragma unroll
    for (int i = 0; i < 4; ++i) {
      int mr = m * 16 + kg * 4 + i;
      float g = accg[m][i] * sg;
      float u = accu[m][i] * su;
      float h = g / (1.f + __expf(-g)) * u;
      hb[(long)(m0 + mr) * II + n_abs] = f2b_rne(h);
    }
  }
}

// ---------------------------------------------------- routed experts: down
__global__ __launch_bounds__(256) void k_moe_down(const ushort* __restrict__ hrt,
                                                  const int* __restrict__ down_p,
                                                  const float* __restrict__ down_s,
                                                  const int* __restrict__ cnt,
                                                  const int* __restrict__ tok,
                                                  const float* __restrict__ tokg,
                                                  float* __restrict__ out) {
  const int e = blockIdx.z;
  const int ne = cnt[e];
  const int m0 = blockIdx.y * 64;
  if (m0 >= ne) return;
  const int n0 = blockIdx.x * 64;      // over DD
  const int tid = threadIdx.x;
  __shared__ ushort A[64][72];
  __shared__ ushort B[64][72];
  __shared__ int rows[64];
  __shared__ int trow[64];
  __shared__ float tg[64];
  if (tid < 64) {
    int s = m0 + tid;
    int valid = (s < ne);
    rows[tid] = valid ? (e * TT + s) : -1;
    trow[tid] = valid ? tok[e * TT + s] : 0;
    tg[tid]   = valid ? tokg[e * TT + s] : 0.f;
  }
  const int* dp = down_p + (long)e * PP;
  f32x4 acc[4];
#pragma unroll
  for (int m = 0; m < 4; ++m) acc[m] = {0.f,0.f,0.f,0.f};
  const int lane = tid & 63, wid = tid >> 6;
  const int col = lane & 15, kg = lane >> 4;
  for (int kt = 0; kt < II / 64; ++kt) {
    int k0 = kt * 64;
    __syncthreads();
    stage_a(hrt, II, rows, k0, A, tid);
    stage_tern(dp, n0, k0, II, B, tid);
    __syncthreads();
#pragma unroll
    for (int kh = 0; kh < 2; ++kh) {
      int kc = kh * 32 + kg * 8;
      bf16x8 bv = *(const bf16x8*)&B[wid * 16 + col][kc];
#pragma unroll
      for (int m = 0; m < 4; ++m) {
        bf16x8 av = *(const bf16x8*)&A[m * 16 + col][kc];
        acc[m] = __builtin_amdgcn_mfma_f32_16x16x32_bf16(av, bv, acc[m], 0, 0, 0);
      }
    }
  }
  const int n_abs = n0 + wid * 16 + col;
  const float sd = down_s[(long)e * DD + n_abs];
#pragma unroll
  for (int m = 0; m < 4; ++m) {
#pragma unroll
    for (int i = 0; i < 4; ++i) {
      int mr = m * 16 + kg * 4 + i;
      if (m0 + mr < ne) {
        float v = acc[m][i] * sd * tg[mr];
        atomicAdd(&out[(long)trow[mr] * DD + n_abs], v);
      }
    }
  }
}

// ---------------------------------------------------------------- launch
extern "C" void kernel_launch(void* const* d_in, const int* in_sizes, int n_in,
                              void* d_out, int out_size, void* d_ws, size_t ws_size,
                              hipStream_t stream) {
  const float* x        = (const float*)d_in[0];
  const float* router_w = (const float*)d_in[1];
  const int*   gate_p   = (const int*)d_in[2];
  const int*   up_p     = (const int*)d_in[3];
  const int*   down_p   = (const int*)d_in[4];
  const float* gate_s   = (const float*)d_in[5];
  const float* up_s     = (const float*)d_in[6];
  const float* down_s   = (const float*)d_in[7];
  const int*   shg      = (const int*)d_in[8];
  const int*   shu      = (const int*)d_in[9];
  const int*   shd      = (const int*)d_in[10];
  const float* shg_s    = (const float*)d_in[11];
  const float* shu_s    = (const float*)d_in[12];
  const float* shd_s    = (const float*)d_in[13];
  float* out = (float*)d_out;

  char* ws = (char*)d_ws;
  int*    cnt  = (int*)ws;                                  // 32 B
  int*    tok  = (int*)(ws + 1024);                         // 8 KB
  float*  tokg = (float*)(ws + 1024 + 8192);                // 8 KB
  ushort* xb   = (ushort*)(ws + 32768);                     // 1 MB
  ushort* hsh  = (ushort*)(ws + 32768 + 1048576);           // 2.88 MB
  ushort* hrt  = (ushort*)(ws + 32768 + 1048576 + 2883584); // 23 MB

  hipMemsetAsync(cnt, 0, 64, stream);
  k_router<<<TT, 64, 0, stream>>>(x, router_w, cnt, tok, tokg);
  k_xcast<<<(TT * DD) / (256 * 8), 256, 0, stream>>>(x, xb);
  k_sh_gateup<<<dim3(II / 64, TT / 64), 256, 0, stream>>>(xb, shg, shu, shg_s, shu_s, hsh);
  k_sh_down<<<dim3(DD / 64, TT / 64), 256, 0, stream>>>(hsh, shd, shd_s, out);
  k_moe_gateup<<<dim3(II / 64, TT / 64, EE), 256, 0, stream>>>(xb, gate_p, up_p, gate_s, up_s,
                                                               cnt, tok, hrt);
  k_moe_down<<<dim3(DD / 64, TT / 64, EE), 256, 0, stream>>>(hrt, down_p, down_s,
                                                             cnt, tok, tokg, out);
}

// Round 5
// 1000.410 us; speedup vs baseline: 1.0172x; 1.0172x over previous
//
#include <hip/hip_runtime.h>
#include <hip/hip_bf16.h>
#include <stdint.h>

#define TT 256
#define DD 2048
#define II 5632
#define EE 8
#define PP 2306868   // (II*DD + 4) / 5

typedef __attribute__((ext_vector_type(8))) short bf16x8;
typedef __attribute__((ext_vector_type(4))) float f32x4;
typedef unsigned int uint;

__device__ __forceinline__ ushort f2b_rne(float f) {
  __hip_bfloat16 h = __float2bfloat16(f);
  return __builtin_bit_cast(ushort, h);
}

__device__ __forceinline__ uint pk_bf16(float lo, float hi) {
  uint r;
  asm("v_cvt_pk_bf16_f32 %0, %1, %2" : "=v"(r) : "v"(lo), "v"(hi));
  return r;
}

__device__ __forceinline__ bf16x8 ld_a(const ushort* p) {
  uint4 v = *(const uint4*)p;
  return __builtin_bit_cast(bf16x8, v);
}

// ---- ternary fragment: 8 consecutive digits starting at flat index q = 5*i0 + ph
// digit f = (packed[f/5] / 3^(f%5)) % 3; weight = digit - 1
__device__ __forceinline__ bf16x8 tern_frag(const int* __restrict__ pk, uint i0, uint ph) {
  uint p0 = (uint)pk[i0], p1 = (uint)pk[i0 + 1], p2 = (uint)pk[i0 + 2];
  uint P = p0 + 243u * p1 + 59049u * p2;         // 15 base-3 digits, < 2^24
  uint c1 = P / 3u, c2 = c1 / 3u, c3 = c2 / 3u, c4 = c3 / 3u;
  uint Q = ph == 0 ? P : (ph == 1 ? c1 : (ph == 2 ? c2 : (ph == 3 ? c3 : c4)));
  uint w0, w1, w2, w3;
#define DIGPAIR(wout) { uint qa = Q / 3u; float flo = (float)(int)(Q - 3u * qa) - 1.0f; \
    uint qb = qa / 3u; float fhi = (float)(int)(qa - 3u * qb) - 1.0f; Q = qb;          \
    wout = pk_bf16(flo, fhi); }
  DIGPAIR(w0) DIGPAIR(w1) DIGPAIR(w2) DIGPAIR(w3)
#undef DIGPAIR
  uint4 u = make_uint4(w0, w1, w2, w3);
  return __builtin_bit_cast(bf16x8, u);
}

// ---- int8-in-int32 fragment: 8 consecutive ints -> bf16 (exact, |v|<=128)
__device__ __forceinline__ bf16x8 i8_frag(const int* __restrict__ w, long off) {
  int4 a = *(const int4*)(w + off);
  int4 b = *(const int4*)(w + off + 4);
  uint4 u;
  u.x = pk_bf16((float)a.x, (float)a.y);
  u.y = pk_bf16((float)a.z, (float)a.w);
  u.z = pk_bf16((float)b.x, (float)b.y);
  u.w = pk_bf16((float)b.z, (float)b.w);
  return __builtin_bit_cast(bf16x8, u);
}

// --------------------------------------------- router + x->bf16 cast (fused)
__global__ __launch_bounds__(64) void k_router(const float* __restrict__ x,
                                               const float* __restrict__ rw,
                                               int* __restrict__ cnt,
                                               int* __restrict__ tok,
                                               float* __restrict__ tokg,
                                               ushort* __restrict__ xb) {
  const int t = blockIdx.x;
  const int lane = threadIdx.x;
  const float* xp = x + (long)t * DD;
  ushort* xbp = xb + (long)t * DD;
  // cast this token's row to bf16
#pragma unroll
  for (int it = 0; it < DD / (64 * 8); ++it) {
    int d = lane * 8 + it * 512;
    float4 a = *(const float4*)(xp + d);
    float4 b = *(const float4*)(xp + d + 4);
    ushort o[8];
    o[0] = f2b_rne(a.x); o[1] = f2b_rne(a.y); o[2] = f2b_rne(a.z); o[3] = f2b_rne(a.w);
    o[4] = f2b_rne(b.x); o[5] = f2b_rne(b.y); o[6] = f2b_rne(b.z); o[7] = f2b_rne(b.w);
    *(uint4*)(xbp + d) = *(uint4*)&o[0];
  }
  // router logits
  float lg[EE];
#pragma unroll
  for (int e = 0; e < EE; ++e) {
    const float* wp = rw + e * DD;
    float acc = 0.f;
    for (int d = lane; d < DD; d += 64) acc += xp[d] * wp[d];
#pragma unroll
    for (int off = 32; off > 0; off >>= 1) acc += __shfl_down(acc, off, 64);
    lg[e] = acc;
  }
  if (lane == 0) {
    int e1 = 0; float v1 = lg[0];
#pragma unroll
    for (int e = 1; e < EE; ++e) if (lg[e] > v1) { v1 = lg[e]; e1 = e; }
    int e2 = -1; float v2 = -3.4e38f;
#pragma unroll
    for (int e = 0; e < EE; ++e) if (e != e1 && lg[e] > v2) { v2 = lg[e]; e2 = e; }
    float ex2 = __expf(v2 - v1);
    float inv = 1.f / (1.f + ex2);
    int s1 = atomicAdd(&cnt[e1], 1);
    tok[e1 * TT + s1] = t; tokg[e1 * TT + s1] = inv;
    int s2 = atomicAdd(&cnt[e2], 1);
    tok[e2 * TT + s2] = t; tokg[e2 * TT + s2] = ex2 * inv;
  }
}

// ------------------------------------------------ all gate/up GEMMs (fused)
// grid (88, 4, 9): z=0..7 routed expert e=z (m0=y*64, token-gathered A);
//                  z=8 shared (y<2, M=128, B-frag reused across 8 m-frags)
__global__ __launch_bounds__(256) void k_gateup_all(const ushort* __restrict__ xb,
                                                    const int* __restrict__ cnt,
                                                    const int* __restrict__ tok,
                                                    const int* __restrict__ gate_p,
                                                    const int* __restrict__ up_p,
                                                    const float* __restrict__ gate_s,
                                                    const float* __restrict__ up_s,
                                                    const int* __restrict__ shg,
                                                    const int* __restrict__ shu,
                                                    const float* __restrict__ shg_s,
                                                    const float* __restrict__ shu_s,
                                                    ushort* __restrict__ hsh,
                                                    ushort* __restrict__ hrt) {
  const int n0 = blockIdx.x * 64;
  const int tid = threadIdx.x;
  const int lane = tid & 63, wid = tid >> 6;
  const int col = lane & 15, kg8 = (lane >> 4) * 8;
  const int n_lane = n0 + wid * 16 + col;
  const int z = blockIdx.z;

  if (z == 8) {                       // ---------------- shared expert
    if (blockIdx.y >= 2) return;
    const int m0 = blockIdx.y * 128;
    const long nd = (long)n_lane * DD;
    f32x4 ag[8], au[8];
#pragma unroll
    for (int m = 0; m < 8; ++m) { ag[m] = {0.f,0.f,0.f,0.f}; au[m] = {0.f,0.f,0.f,0.f}; }
#pragma unroll 1
    for (int kt = 0; kt < DD / 64; ++kt) {
#pragma unroll
      for (int kh = 0; kh < 2; ++kh) {
        const int kf = kt * 64 + kh * 32 + kg8;
        bf16x8 bg = i8_frag(shg, nd + kf);
        bf16x8 bu = i8_frag(shu, nd + kf);
#pragma unroll
        for (int m = 0; m < 8; ++m) {
          bf16x8 av = ld_a(xb + (long)(m0 + m * 16 + col) * DD + kf);
          ag[m] = __builtin_amdgcn_mfma_f32_16x16x32_bf16(av, bg, ag[m], 0, 0, 0);
          au[m] = __builtin_amdgcn_mfma_f32_16x16x32_bf16(av, bu, au[m], 0, 0, 0);
        }
      }
    }
    const float sg = shg_s[n_lane];
    const float su = shu_s[n_lane];
#pragma unroll
    for (int m = 0; m < 8; ++m)
#pragma unroll
      for (int i = 0; i < 4; ++i) {
        int mr = m0 + m * 16 + (lane >> 4) * 4 + i;
        float g = ag[m][i] * sg, u = au[m][i] * su;
        float h = g / (1.f + __expf(-g)) * u;
        hsh[(long)mr * II + n_lane] = f2b_rne(h);
      }
  } else {                            // ---------------- routed expert e=z
    const int e = z;
    const int ne = cnt[e];
    const int m0 = blockIdx.y * 64;
    if (m0 >= ne) return;
    long arow[4];
#pragma unroll
    for (int m = 0; m < 4; ++m) {
      int s = m0 + m * 16 + col;
      if (s >= ne) s = ne - 1;        // clamp: garbage rows discarded downstream
      arow[m] = (long)tok[e * TT + s] * DD;
    }
    const int* gp = gate_p + (long)e * PP;
    const int* up = up_p + (long)e * PP;
    const uint nd = (uint)n_lane * DD;
    f32x4 ag[4], au[4];
#pragma unroll
    for (int m = 0; m < 4; ++m) { ag[m] = {0.f,0.f,0.f,0.f}; au[m] = {0.f,0.f,0.f,0.f}; }
#pragma unroll 1
    for (int kt = 0; kt < DD / 64; ++kt) {
#pragma unroll
      for (int kh = 0; kh < 2; ++kh) {
        const int kf = kt * 64 + kh * 32 + kg8;
        const uint q = nd + (uint)kf;
        const uint i0 = q / 5u;
        const uint ph = q - 5u * i0;
        bf16x8 bg = tern_frag(gp, i0, ph);
        bf16x8 bu = tern_frag(up, i0, ph);
#pragma unroll
        for (int m = 0; m < 4; ++m) {
          bf16x8 av = ld_a(xb + arow[m] + kf);
          ag[m] = __builtin_amdgcn_mfma_f32_16x16x32_bf16(av, bg, ag[m], 0, 0, 0);
          au[m] = __builtin_amdgcn_mfma_f32_16x16x32_bf16(av, bu, au[m], 0, 0, 0);
        }
      }
    }
    const float sg = gate_s[(long)e * II + n_lane];
    const float su = up_s[(long)e * II + n_lane];
    ushort* hb = hrt + (long)e * TT * II;
#pragma unroll
    for (int m = 0; m < 4; ++m)
#pragma unroll
      for (int i = 0; i < 4; ++i) {
        int mr = m0 + m * 16 + (lane >> 4) * 4 + i;
        float g = ag[m][i] * sg, u = au[m][i] * su;
        float h = g / (1.f + __expf(-g)) * u;
        hb[(long)mr * II + n_lane] = f2b_rne(h);
      }
  }
}

// -------------------------------------------------- all down GEMMs (fused)
// grid (32, 4, 20): z=0..15 routed (e=z>>1, ks=z&1, split-K 2);
//                   z=16..19 shared (ks=z-16, split-K 4, y<2, M=128)
__global__ __launch_bounds__(256) void k_down_all(const ushort* __restrict__ hsh,
                                                  const ushort* __restrict__ hrt,
                                                  const int* __restrict__ down_p,
                                                  const float* __restrict__ down_s,
                                                  const int* __restrict__ shd,
                                                  const float* __restrict__ shd_s,
                                                  const int* __restrict__ cnt,
                                                  const int* __restrict__ tok,
                                                  const float* __restrict__ tokg,
                                                  float* __restrict__ out) {
  const int n0 = blockIdx.x * 64;
  const int tid = threadIdx.x;
  const int lane = tid & 63, wid = tid >> 6;
  const int col = lane & 15, kg8 = (lane >> 4) * 8;
  const int n_lane = n0 + wid * 16 + col;
  const int z = blockIdx.z;

  if (z >= 16) {                      // ---------------- shared expert
    if (blockIdx.y >= 2) return;
    const int ks = z - 16;
    const int m0 = blockIdx.y * 128;
    const long nd = (long)n_lane * II;
    f32x4 acc[8];
#pragma unroll
    for (int m = 0; m < 8; ++m) acc[m] = {0.f,0.f,0.f,0.f};
#pragma unroll 1
    for (int kt = ks * 22; kt < ks * 22 + 22; ++kt) {
#pragma unroll
      for (int kh = 0; kh < 2; ++kh) {
        const int kf = kt * 64 + kh * 32 + kg8;
        bf16x8 bv = i8_frag(shd, nd + kf);
#pragma unroll
        for (int m = 0; m < 8; ++m) {
          bf16x8 av = ld_a(hsh + (long)(m0 + m * 16 + col) * II + kf);
          acc[m] = __builtin_amdgcn_mfma_f32_16x16x32_bf16(av, bv, acc[m], 0, 0, 0);
        }
      }
    }
    const float sd = shd_s[n_lane];
#pragma unroll
    for (int m = 0; m < 8; ++m)
#pragma unroll
      for (int i = 0; i < 4; ++i) {
        int mr = m0 + m * 16 + (lane >> 4) * 4 + i;
        atomicAdd(&out[(long)mr * DD + n_lane], acc[m][i] * sd);
      }
  } else {                            // ---------------- routed expert
    const int e = z >> 1, ks = z & 1;
    const int ne = cnt[e];
    const int m0 = blockIdx.y * 64;
    if (m0 >= ne) return;
    const int* dp = down_p + (long)e * PP;
    const ushort* abase = hrt + (long)(e * TT + m0 + col) * II;
    const uint nd = (uint)n_lane * II;
    f32x4 acc[4];
#pragma unroll
    for (int m = 0; m < 4; ++m) acc[m] = {0.f,0.f,0.f,0.f};
#pragma unroll 1
    for (int kt = ks * 44; kt < ks * 44 + 44; ++kt) {
#pragma unroll
      for (int kh = 0; kh < 2; ++kh) {
        const int kf = kt * 64 + kh * 32 + kg8;
        const uint q = nd + (uint)kf;
        const uint i0 = q / 5u;
        const uint ph = q - 5u * i0;
        bf16x8 bv = tern_frag(dp, i0, ph);
#pragma unroll
        for (int m = 0; m < 4; ++m) {
          bf16x8 av = ld_a(abase + (long)m * 16 * II + kf);
          acc[m] = __builtin_amdgcn_mfma_f32_16x16x32_bf16(av, bv, acc[m], 0, 0, 0);
        }
      }
    }
    const float sd = down_s[(long)e * DD + n_lane];
#pragma unroll
    for (int m = 0; m < 4; ++m)
#pragma unroll
      for (int i = 0; i < 4; ++i) {
        int mr = m0 + m * 16 + (lane >> 4) * 4 + i;
        if (mr < ne) {
          float v = acc[m][i] * sd * tokg[e * TT + mr];
          atomicAdd(&out[(long)tok[e * TT + mr] * DD + n_lane], v);
        }
      }
  }
}

// ---------------------------------------------------------------- launch
extern "C" void kernel_launch(void* const* d_in, const int* in_sizes, int n_in,
                              void* d_out, int out_size, void* d_ws, size_t ws_size,
                              hipStream_t stream) {
  const float* x        = (const float*)d_in[0];
  const float* router_w = (const float*)d_in[1];
  const int*   gate_p   = (const int*)d_in[2];
  const int*   up_p     = (const int*)d_in[3];
  const int*   down_p   = (const int*)d_in[4];
  const float* gate_s   = (const float*)d_in[5];
  const float* up_s     = (const float*)d_in[6];
  const float* down_s   = (const float*)d_in[7];
  const int*   shg      = (const int*)d_in[8];
  const int*   shu      = (const int*)d_in[9];
  const int*   shd      = (const int*)d_in[10];
  const float* shg_s    = (const float*)d_in[11];
  const float* shu_s    = (const float*)d_in[12];
  const float* shd_s    = (const float*)d_in[13];
  float* out = (float*)d_out;

  char* ws = (char*)d_ws;
  int*    cnt  = (int*)ws;                                   // 64 B
  int*    tok  = (int*)(ws + 1024);                          // 8 KB
  float*  tokg = (float*)(ws + 9216);                        // 8 KB
  ushort* xb   = (ushort*)(ws + 32768);                      // 1 MB
  ushort* hsh  = (ushort*)(ws + 32768 + 1048576);            // 2.88 MB
  ushort* hrt  = (ushort*)(ws + 32768 + 1048576 + 2883584);  // 23 MB

  hipMemsetAsync(cnt, 0, 64, stream);
  hipMemsetAsync(out, 0, (size_t)TT * DD * 4, stream);
  k_router<<<TT, 64, 0, stream>>>(x, router_w, cnt, tok, tokg, xb);
  k_gateup_all<<<dim3(88, 4, 9), 256, 0, stream>>>(xb, cnt, tok, gate_p, up_p, gate_s, up_s,
                                                   shg, shu, shg_s, shu_s, hsh, hrt);
  k_down_all<<<dim3(32, 4, 20), 256, 0, stream>>>(hsh, hrt, down_p, down_s, shd, shd_s,
                                                  cnt, tok, tokg, out);
}

// Round 6
// 971.003 us; speedup vs baseline: 1.0480x; 1.0303x over previous
//
#include <hip/hip_runtime.h>
#include <hip/hip_bf16.h>
#include <stdint.h>

#define TT 256
#define DD 2048
#define II 5632
#define EE 8
#define PP 2306868   // (II*DD + 4) / 5

typedef __attribute__((ext_vector_type(8))) short bf16x8;
typedef __attribute__((ext_vector_type(4))) float f32x4;
typedef unsigned int uint;

__device__ __forceinline__ ushort f2b_rne(float f) {
  __hip_bfloat16 h = __float2bfloat16(f);
  return __builtin_bit_cast(ushort, h);
}

__device__ __forceinline__ uint pk_bf16(float lo, float hi) {
  uint r;
  asm("v_cvt_pk_bf16_f32 %0, %1, %2" : "=v"(r) : "v"(lo), "v"(hi));
  return r;
}

__device__ __forceinline__ bf16x8 ld_a(const ushort* p) {
  uint4 v = *(const uint4*)p;
  return __builtin_bit_cast(bf16x8, v);
}

// ---- ternary digit chain: 8 consecutive digits from 3 packed ints, phase ph
// digit f = (packed[f/5] / 3^(f%5)) % 3; weight = digit - 1  (validated on-device r5)
__device__ __forceinline__ bf16x8 tern_digits(uint p0, uint p1, uint p2, uint ph) {
  uint P = p0 + 243u * p1 + 59049u * p2;         // 15 base-3 digits, < 2^24
  uint c1 = P / 3u, c2 = c1 / 3u, c3 = c2 / 3u, c4 = c3 / 3u;
  uint Q = ph == 0 ? P : (ph == 1 ? c1 : (ph == 2 ? c2 : (ph == 3 ? c3 : c4)));
  uint w0, w1, w2, w3;
#define DIGPAIR(wout) { uint qa = Q / 3u; float flo = (float)(int)(Q - 3u * qa) - 1.0f; \
    uint qb = qa / 3u; float fhi = (float)(int)(qa - 3u * qb) - 1.0f; Q = qb;          \
    wout = pk_bf16(flo, fhi); }
  DIGPAIR(w0) DIGPAIR(w1) DIGPAIR(w2) DIGPAIR(w3)
#undef DIGPAIR
  uint4 u = make_uint4(w0, w1, w2, w3);
  return __builtin_bit_cast(bf16x8, u);
}

// ---- stage one 256-digit chunk of 64 ternary rows into LDS (coalesced int4 loads)
// LDS: lw[r*60 + j], j in [0,56); row r covers ints [a_r, a_r+56) where
// a_r = floor((n0+r)*din + c0, /5) & ~3  (56 ints cover the 53-int worst-case window)
__device__ __forceinline__ void stage_tern_chunk(const int* __restrict__ pk,
                                                 int n0, int din, int c0,
                                                 int* lw, int tid) {
  const int j = tid & 15;
  if (j < 14) {
#pragma unroll
    for (int it = 0; it < 4; ++it) {
      int r = it * 16 + (tid >> 4);
      uint q0 = (uint)(n0 + r) * (uint)din + (uint)c0;
      uint a = (q0 / 5u) & ~3u;
      uint idx = a + (uint)(j * 4);
      if (idx > (uint)(PP - 4)) idx = (uint)(PP - 4);  // tail clamp: clamped slots never read
      int4 v = *(const int4*)(pk + idx);
      *(int4*)&lw[r * 60 + j * 4] = v;
    }
  }
}

// ---- stage one 128-int chunk of 64 int8 rows as bf16 into LDS (coalesced, XOR-swizzled)
// LDS row stride 256B; byte ^= (row&7)<<4 -> even bank coverage for ds_read_b128
__device__ __forceinline__ void stage_i8_chunk(const int* __restrict__ w,
                                               int n0, int din, int c0,
                                               ushort* lb, int tid) {
  const int lane = tid & 63, wid = tid >> 6;
#pragma unroll
  for (int it = 0; it < 8; ++it) {
    int r = it * 8 + wid * 2 + (lane >> 5);      // 0..63
    int jj = (lane & 31) * 4;                    // int index within 128
    int4 v = *(const int4*)(w + (long)(n0 + r) * din + c0 + jj);
    uint2 o;
    o.x = pk_bf16((float)v.x, (float)v.y);
    o.y = pk_bf16((float)v.z, (float)v.w);
    uint byte = (uint)(r * 256 + jj * 2);
    byte ^= (uint)((r & 7) << 4);
    *(uint2*)((char*)lb + byte) = o;
  }
}

__device__ __forceinline__ bf16x8 ld_b_sw(const ushort* lb, int row, int klocal) {
  uint byte = (uint)(row * 256 + klocal * 2);
  byte ^= (uint)((row & 7) << 4);
  uint4 v = *(const uint4*)((const char*)lb + byte);
  return __builtin_bit_cast(bf16x8, v);
}

// --------------------------------------------- router + x->bf16 cast (fused)
__global__ __launch_bounds__(64) void k_router(const float* __restrict__ x,
                                               const float* __restrict__ rw,
                                               int* __restrict__ cnt,
                                               int* __restrict__ tok,
                                               float* __restrict__ tokg,
                                               ushort* __restrict__ xb) {
  const int t = blockIdx.x;
  const int lane = threadIdx.x;
  const float* xp = x + (long)t * DD;
  ushort* xbp = xb + (long)t * DD;
#pragma unroll
  for (int it = 0; it < DD / (64 * 8); ++it) {
    int d = lane * 8 + it * 512;
    float4 a = *(const float4*)(xp + d);
    float4 b = *(const float4*)(xp + d + 4);
    ushort o[8];
    o[0] = f2b_rne(a.x); o[1] = f2b_rne(a.y); o[2] = f2b_rne(a.z); o[3] = f2b_rne(a.w);
    o[4] = f2b_rne(b.x); o[5] = f2b_rne(b.y); o[6] = f2b_rne(b.z); o[7] = f2b_rne(b.w);
    *(uint4*)(xbp + d) = *(uint4*)&o[0];
  }
  float lg[EE];
#pragma unroll
  for (int e = 0; e < EE; ++e) {
    const float* wp = rw + e * DD;
    float acc = 0.f;
    for (int d = lane; d < DD; d += 64) acc += xp[d] * wp[d];
#pragma unroll
    for (int off = 32; off > 0; off >>= 1) acc += __shfl_down(acc, off, 64);
    lg[e] = acc;
  }
  if (lane == 0) {
    int e1 = 0; float v1 = lg[0];
#pragma unroll
    for (int e = 1; e < EE; ++e) if (lg[e] > v1) { v1 = lg[e]; e1 = e; }
    int e2 = -1; float v2 = -3.4e38f;
#pragma unroll
    for (int e = 0; e < EE; ++e) if (e != e1 && lg[e] > v2) { v2 = lg[e]; e2 = e; }
    float ex2 = __expf(v2 - v1);
    float inv = 1.f / (1.f + ex2);
    int s1 = atomicAdd(&cnt[e1], 1);
    tok[e1 * TT + s1] = t; tokg[e1 * TT + s1] = inv;
    int s2 = atomicAdd(&cnt[e2], 1);
    tok[e2 * TT + s2] = t; tokg[e2 * TT + s2] = ex2 * inv;
  }
}

// ------------------------------------------------ all gate/up GEMMs (fused)
// grid (88, 4, 9): z=0..7 routed expert e=z (m0=y*64, token-gathered A, LDS-staged
// ternary); z=8 shared (y<2, M=128, LDS-staged int8->bf16)
__global__ __launch_bounds__(256) void k_gateup_all(const ushort* __restrict__ xb,
                                                    const int* __restrict__ cnt,
                                                    const int* __restrict__ tok,
                                                    const int* __restrict__ gate_p,
                                                    const int* __restrict__ up_p,
                                                    const float* __restrict__ gate_s,
                                                    const float* __restrict__ up_s,
                                                    const int* __restrict__ shg,
                                                    const int* __restrict__ shu,
                                                    const float* __restrict__ shg_s,
                                                    const float* __restrict__ shu_s,
                                                    ushort* __restrict__ hsh,
                                                    ushort* __restrict__ hrt) {
  __shared__ __align__(16) char smem[32768];
  const int n0 = blockIdx.x * 64;
  const int tid = threadIdx.x;
  const int lane = tid & 63, wid = tid >> 6;
  const int col = lane & 15, kg8 = (lane >> 4) * 8;
  const int lrow = wid * 16 + col;
  const int n_lane = n0 + lrow;
  const int z = blockIdx.z;

  if (z == 8) {                       // ---------------- shared expert
    if (blockIdx.y >= 2) return;
    const int m0 = blockIdx.y * 128;
    ushort* lbg = (ushort*)smem;
    ushort* lbu = lbg + 64 * 128;
    f32x4 ag[8], au[8];
#pragma unroll
    for (int m = 0; m < 8; ++m) { ag[m] = {0.f,0.f,0.f,0.f}; au[m] = {0.f,0.f,0.f,0.f}; }
#pragma unroll 1
    for (int c = 0; c < 16; ++c) {
      __syncthreads();
      stage_i8_chunk(shg, n0, DD, c * 128, lbg, tid);
      stage_i8_chunk(shu, n0, DD, c * 128, lbu, tid);
      __syncthreads();
#pragma unroll
      for (int kk = 0; kk < 4; ++kk) {
        const int klocal = kk * 32 + kg8;
        bf16x8 bg = ld_b_sw(lbg, lrow, klocal);
        bf16x8 bu = ld_b_sw(lbu, lrow, klocal);
        const int kf = c * 128 + klocal;
#pragma unroll
        for (int m = 0; m < 8; ++m) {
          bf16x8 av = ld_a(xb + (long)(m0 + m * 16 + col) * DD + kf);
          ag[m] = __builtin_amdgcn_mfma_f32_16x16x32_bf16(av, bg, ag[m], 0, 0, 0);
          au[m] = __builtin_amdgcn_mfma_f32_16x16x32_bf16(av, bu, au[m], 0, 0, 0);
        }
      }
    }
    const float sg = shg_s[n_lane];
    const float su = shu_s[n_lane];
#pragma unroll
    for (int m = 0; m < 8; ++m)
#pragma unroll
      for (int i = 0; i < 4; ++i) {
        int mr = m0 + m * 16 + (lane >> 4) * 4 + i;
        float g = ag[m][i] * sg, u = au[m][i] * su;
        float h = g / (1.f + __expf(-g)) * u;
        hsh[(long)mr * II + n_lane] = f2b_rne(h);
      }
  } else {                            // ---------------- routed expert e=z
    const int e = z;
    const int ne = cnt[e];
    const int m0 = blockIdx.y * 64;
    if (m0 >= ne) return;
    long arow[4];
#pragma unroll
    for (int m = 0; m < 4; ++m) {
      int s = m0 + m * 16 + col;
      if (s >= ne) s = ne - 1;        // clamp: garbage rows discarded downstream
      arow[m] = (long)tok[e * TT + s] * DD;
    }
    int* lwg = (int*)smem;            // 64*60 ints
    int* lwu = lwg + 64 * 60;
    const int* gp = gate_p + (long)e * PP;
    const int* up = up_p + (long)e * PP;
    const uint nb = (uint)n_lane * DD;
    f32x4 ag[4], au[4];
#pragma unroll
    for (int m = 0; m < 4; ++m) { ag[m] = {0.f,0.f,0.f,0.f}; au[m] = {0.f,0.f,0.f,0.f}; }
#pragma unroll 1
    for (int c = 0; c < 8; ++c) {
      __syncthreads();
      stage_tern_chunk(gp, n0, DD, c * 256, lwg, tid);
      stage_tern_chunk(up, n0, DD, c * 256, lwu, tid);
      __syncthreads();
      const uint a = ((nb + (uint)(c * 256)) / 5u) & ~3u;
#pragma unroll 2
      for (int kk = 0; kk < 8; ++kk) {
        const int kf = c * 256 + kk * 32 + kg8;
        const uint q = nb + (uint)kf;
        const uint i0 = q / 5u;
        const uint ph = q - 5u * i0;
        const int* pg = lwg + lrow * 60 + (int)(i0 - a);
        const int* pu = lwu + lrow * 60 + (int)(i0 - a);
        bf16x8 bg = tern_digits((uint)pg[0], (uint)pg[1], (uint)pg[2], ph);
        bf16x8 bu = tern_digits((uint)pu[0], (uint)pu[1], (uint)pu[2], ph);
#pragma unroll
        for (int m = 0; m < 4; ++m) {
          bf16x8 av = ld_a(xb + arow[m] + kf);
          ag[m] = __builtin_amdgcn_mfma_f32_16x16x32_bf16(av, bg, ag[m], 0, 0, 0);
          au[m] = __builtin_amdgcn_mfma_f32_16x16x32_bf16(av, bu, au[m], 0, 0, 0);
        }
      }
    }
    const float sg = gate_s[(long)e * II + n_lane];
    const float su = up_s[(long)e * II + n_lane];
    ushort* hb = hrt + (long)e * TT * II;
#pragma unroll
    for (int m = 0; m < 4; ++m)
#pragma unroll
      for (int i = 0; i < 4; ++i) {
        int mr = m0 + m * 16 + (lane >> 4) * 4 + i;
        float g = ag[m][i] * sg, u = au[m][i] * su;
        float h = g / (1.f + __expf(-g)) * u;
        hb[(long)mr * II + n_lane] = f2b_rne(h);
      }
  }
}

// -------------------------------------------------- all down GEMMs (fused)
// grid (32, 4, 20): z=0..15 routed (e=z>>1, ks=z&1: 11 chunks of 256 each);
//                   z=16..19 shared (ks=z-16: 11 chunks of 128 each, y<2, M=128)
__global__ __launch_bounds__(256) void k_down_all(const ushort* __restrict__ hsh,
                                                  const ushort* __restrict__ hrt,
                                                  const int* __restrict__ down_p,
                                                  const float* __restrict__ down_s,
                                                  const int* __restrict__ shd,
                                                  const float* __restrict__ shd_s,
                                                  const int* __restrict__ cnt,
                                                  const int* __restrict__ tok,
                                                  const float* __restrict__ tokg,
                                                  float* __restrict__ out) {
  __shared__ __align__(16) char smem[16384];
  const int n0 = blockIdx.x * 64;
  const int tid = threadIdx.x;
  const int lane = tid & 63, wid = tid >> 6;
  const int col = lane & 15, kg8 = (lane >> 4) * 8;
  const int lrow = wid * 16 + col;
  const int n_lane = n0 + lrow;
  const int z = blockIdx.z;

  if (z >= 16) {                      // ---------------- shared expert
    if (blockIdx.y >= 2) return;
    const int ks = z - 16;
    const int m0 = blockIdx.y * 128;
    ushort* lb = (ushort*)smem;
    f32x4 acc[8];
#pragma unroll
    for (int m = 0; m < 8; ++m) acc[m] = {0.f,0.f,0.f,0.f};
#pragma unroll 1
    for (int cc = 0; cc < 11; ++cc) {
      const int c = ks * 11 + cc;
      __syncthreads();
      stage_i8_chunk(shd, n0, II, c * 128, lb, tid);
      __syncthreads();
#pragma unroll
      for (int kk = 0; kk < 4; ++kk) {
        const int klocal = kk * 32 + kg8;
        bf16x8 bv = ld_b_sw(lb, lrow, klocal);
        const int kf = c * 128 + klocal;
#pragma unroll
        for (int m = 0; m < 8; ++m) {
          bf16x8 av = ld_a(hsh + (long)(m0 + m * 16 + col) * II + kf);
          acc[m] = __builtin_amdgcn_mfma_f32_16x16x32_bf16(av, bv, acc[m], 0, 0, 0);
        }
      }
    }
    const float sd = shd_s[n_lane];
#pragma unroll
    for (int m = 0; m < 8; ++m)
#pragma unroll
      for (int i = 0; i < 4; ++i) {
        int mr = m0 + m * 16 + (lane >> 4) * 4 + i;
        atomicAdd(&out[(long)mr * DD + n_lane], acc[m][i] * sd);
      }
  } else {                            // ---------------- routed expert
    const int e = z >> 1, ks = z & 1;
    const int ne = cnt[e];
    const int m0 = blockIdx.y * 64;
    if (m0 >= ne) return;
    int* lw = (int*)smem;
    const int* dp = down_p + (long)e * PP;
    const ushort* abase = hrt + (long)(e * TT + m0 + col) * II;
    const uint nb = (uint)n_lane * II;
    f32x4 acc[4];
#pragma unroll
    for (int m = 0; m < 4; ++m) acc[m] = {0.f,0.f,0.f,0.f};
#pragma unroll 1
    for (int cc = 0; cc < 11; ++cc) {
      const int c = ks * 11 + cc;
      __syncthreads();
      stage_tern_chunk(dp, n0, II, c * 256, lw, tid);
      __syncthreads();
      const uint a = ((nb + (uint)(c * 256)) / 5u) & ~3u;
#pragma unroll 2
      for (int kk = 0; kk < 8; ++kk) {
        const int kf = c * 256 + kk * 32 + kg8;
        const uint q = nb + (uint)kf;
        const uint i0 = q / 5u;
        const uint ph = q - 5u * i0;
        const int* p = lw + lrow * 60 + (int)(i0 - a);
        bf16x8 bv = tern_digits((uint)p[0], (uint)p[1], (uint)p[2], ph);
#pragma unroll
        for (int m = 0; m < 4; ++m) {
          bf16x8 av = ld_a(abase + (long)m * 16 * II + kf);
          acc[m] = __builtin_amdgcn_mfma_f32_16x16x32_bf16(av, bv, acc[m], 0, 0, 0);
        }
      }
    }
    const float sd = down_s[(long)e * DD + n_lane];
#pragma unroll
    for (int m = 0; m < 4; ++m)
#pragma unroll
      for (int i = 0; i < 4; ++i) {
        int mr = m0 + m * 16 + (lane >> 4) * 4 + i;
        if (mr < ne) {
          float v = acc[m][i] * sd * tokg[e * TT + mr];
          atomicAdd(&out[(long)tok[e * TT + mr] * DD + n_lane], v);
        }
      }
  }
}

// ---------------------------------------------------------------- launch
extern "C" void kernel_launch(void* const* d_in, const int* in_sizes, int n_in,
                              void* d_out, int out_size, void* d_ws, size_t ws_size,
                              hipStream_t stream) {
  const float* x        = (const float*)d_in[0];
  const float* router_w = (const float*)d_in[1];
  const int*   gate_p   = (const int*)d_in[2];
  const int*   up_p     = (const int*)d_in[3];
  const int*   down_p   = (const int*)d_in[4];
  const float* gate_s   = (const float*)d_in[5];
  const float* up_s     = (const float*)d_in[6];
  const float* down_s   = (const float*)d_in[7];
  const int*   shg      = (const int*)d_in[8];
  const int*   shu      = (const int*)d_in[9];
  const int*   shd      = (const int*)d_in[10];
  const float* shg_s    = (const float*)d_in[11];
  const float* shu_s    = (const float*)d_in[12];
  const float* shd_s    = (const float*)d_in[13];
  float* out = (float*)d_out;

  char* ws = (char*)d_ws;
  int*    cnt  = (int*)ws;                                   // 64 B
  int*    tok  = (int*)(ws + 1024);                          // 8 KB
  float*  tokg = (float*)(ws + 9216);                        // 8 KB
  ushort* xb   = (ushort*)(ws + 32768);                      // 1 MB
  ushort* hsh  = (ushort*)(ws + 32768 + 1048576);            // 2.88 MB
  ushort* hrt  = (ushort*)(ws + 32768 + 1048576 + 2883584);  // 23 MB

  hipMemsetAsync(cnt, 0, 64, stream);
  hipMemsetAsync(out, 0, (size_t)TT * DD * 4, stream);
  k_router<<<TT, 64, 0, stream>>>(x, router_w, cnt, tok, tokg, xb);
  k_gateup_all<<<dim3(88, 4, 9), 256, 0, stream>>>(xb, cnt, tok, gate_p, up_p, gate_s, up_s,
                                                   shg, shu, shg_s, shu_s, hsh, hrt);
  k_down_all<<<dim3(32, 4, 20), 256, 0, stream>>>(hsh, hrt, down_p, down_s, shd, shd_s,
                                                  cnt, tok, tokg, out);
}